// Round 1
// baseline (385.717 us; speedup 1.0000x reference)
//
#include <hip/hip_runtime.h>
#include <hip/hip_bf16.h>
#include <stdint.h>

#define N_NODES 150000
#define C_IN 32
#define C_OUT 64
#define K_TAPS 27

typedef __attribute__((ext_vector_type(8))) __bf16 bf16x8;
typedef __attribute__((ext_vector_type(4))) float f32x4;

__device__ __forceinline__ ushort f2bf(float f) {
    union { float f; uint32_t u; } v; v.f = f;
    uint32_t u = v.u;
    return (ushort)((u + 0x7FFFu + ((u >> 16) & 1u)) >> 16);
}

// ---------------------------------------------------------------------------
// Kernel 1: transpose x (32 x 150000 fp32) -> xT (150001 x 32 bf16), zero pad row
// ---------------------------------------------------------------------------
__global__ __launch_bounds__(256) void k_transpose(const float* __restrict__ x,
                                                   ushort* __restrict__ xT) {
    __shared__ float tile[32][65];
    int t = threadIdx.x;
    int nb = blockIdx.x * 64;
    int nl = t & 63, i4 = t >> 6;
#pragma unroll
    for (int rep = 0; rep < 8; ++rep) {
        int i = rep * 4 + i4;
        int n = nb + nl;
        tile[i][nl] = (n < N_NODES) ? x[(size_t)i * N_NODES + n] : 0.0f;
    }
    __syncthreads();
    int nr = t >> 2, c0 = (t & 3) * 8;
    int n = nb + nr;
    if (n <= N_NODES) {  // row N_NODES is the zero-pad row (reads above yield 0)
        uint32_t w[4];
#pragma unroll
        for (int j = 0; j < 4; ++j) {
            ushort lo = f2bf(tile[c0 + 2 * j][nr]);
            ushort hi = f2bf(tile[c0 + 2 * j + 1][nr]);
            w[j] = (uint32_t)lo | ((uint32_t)hi << 16);
        }
        *reinterpret_cast<uint4*>(xT + (size_t)n * 32 + c0) =
            make_uint4(w[0], w[1], w[2], w[3]);
    }
}

// ---------------------------------------------------------------------------
// Kernel 2: reorder W (64,32,27) fp32 -> A_re[o][k*32+i] bf16; zero stats[0..127]
// ---------------------------------------------------------------------------
__global__ __launch_bounds__(256) void k_prep_w(const float* __restrict__ W,
                                                ushort* __restrict__ A_re,
                                                float* __restrict__ stats) {
    int tid = blockIdx.x * 256 + threadIdx.x;
    if (tid < 2 * C_OUT) stats[tid] = 0.0f;
    if (tid < C_OUT * C_IN * K_TAPS) {
        int o = tid / (C_IN * K_TAPS);
        int rem = tid - o * (C_IN * K_TAPS);
        int k = rem / C_IN;
        int i = rem - k * C_IN;
        // A_re index: o*864 + k*32 + i == tid (since rem == k*32+i)
        A_re[tid] = f2bf(W[o * (C_IN * K_TAPS) + i * K_TAPS + k]);
    }
}

// ---------------------------------------------------------------------------
// Kernel 3: gather-GEMM. Block = 4 waves, 256 nodes. Each wave: 64 ch x 64 nodes.
// y written to d_out (fp32, [o][n]); per-channel sum/sumsq atomically accumulated.
// ---------------------------------------------------------------------------
__global__ __launch_bounds__(256) void k_conv(const ushort* __restrict__ xT,
                                              const ushort* __restrict__ A_re,
                                              const int* __restrict__ neigh,
                                              float* __restrict__ y,
                                              float* __restrict__ stats) {
    __shared__ int sidx[256 * K_TAPS];
    int t = threadIdx.x;
    int nblock = blockIdx.x * 256;
    for (int j = t; j < 256 * K_TAPS; j += 256) {
        int ng = nblock + j / K_TAPS;
        sidx[j] = (ng < N_NODES) ? neigh[(size_t)nblock * K_TAPS + j] : N_NODES;
    }
    __syncthreads();

    int wid = t >> 6, lane = t & 63;
    int l15 = lane & 15, quad = lane >> 4;
    int qoff = quad * 8;

    int ib[4];
#pragma unroll
    for (int g = 0; g < 4; ++g) ib[g] = (wid * 64 + g * 16 + l15) * K_TAPS;
    int aoff[4];
#pragma unroll
    for (int m = 0; m < 4; ++m) aoff[m] = (m * 16 + l15) * (C_IN * K_TAPS) + qoff;

    f32x4 acc[4][4];
#pragma unroll
    for (int m = 0; m < 4; ++m)
#pragma unroll
        for (int g = 0; g < 4; ++g) acc[m][g] = (f32x4){0.f, 0.f, 0.f, 0.f};

    bf16x8 bcur[4], bnxt[4], acur[4], anxt[4];
#pragma unroll
    for (int g = 0; g < 4; ++g)
        bcur[g] = *reinterpret_cast<const bf16x8*>(xT + (size_t)sidx[ib[g]] * 32 + qoff);
#pragma unroll
    for (int m = 0; m < 4; ++m)
        acur[m] = *reinterpret_cast<const bf16x8*>(A_re + aoff[m]);

#pragma unroll 2
    for (int k = 0; k < K_TAPS - 1; ++k) {
#pragma unroll
        for (int g = 0; g < 4; ++g)
            bnxt[g] = *reinterpret_cast<const bf16x8*>(
                xT + (size_t)sidx[ib[g] + k + 1] * 32 + qoff);
#pragma unroll
        for (int m = 0; m < 4; ++m)
            anxt[m] = *reinterpret_cast<const bf16x8*>(A_re + aoff[m] + (k + 1) * 32);
#pragma unroll
        for (int m = 0; m < 4; ++m)
#pragma unroll
            for (int g = 0; g < 4; ++g)
                acc[m][g] = __builtin_amdgcn_mfma_f32_16x16x32_bf16(
                    acur[m], bcur[g], acc[m][g], 0, 0, 0);
#pragma unroll
        for (int g = 0; g < 4; ++g) bcur[g] = bnxt[g];
#pragma unroll
        for (int m = 0; m < 4; ++m) acur[m] = anxt[m];
    }
#pragma unroll
    for (int m = 0; m < 4; ++m)
#pragma unroll
        for (int g = 0; g < 4; ++g)
            acc[m][g] = __builtin_amdgcn_mfma_f32_16x16x32_bf16(
                acur[m], bcur[g], acc[m][g], 0, 0, 0);

    // store y tile (C/D layout: col=lane&15 -> node, row=quad*4+reg -> channel)
#pragma unroll
    for (int m = 0; m < 4; ++m) {
        int obase = m * 16 + quad * 4;
#pragma unroll
        for (int g = 0; g < 4; ++g) {
            int n = nblock + wid * 64 + g * 16 + l15;
            if (n < N_NODES) {
#pragma unroll
                for (int r = 0; r < 4; ++r)
                    y[(size_t)(obase + r) * N_NODES + n] = acc[m][g][r];
            }
        }
    }

    // per-channel partial sums (padding nodes contribute exact 0 -> harmless)
#pragma unroll
    for (int m = 0; m < 4; ++m) {
#pragma unroll
        for (int r = 0; r < 4; ++r) {
            float s = 0.f, sq = 0.f;
#pragma unroll
            for (int g = 0; g < 4; ++g) {
                float v = acc[m][g][r];
                s += v;
                sq += v * v;
            }
#pragma unroll
            for (int d = 1; d < 16; d <<= 1) {
                s += __shfl_xor(s, d);
                sq += __shfl_xor(sq, d);
            }
            if (l15 == 0) {
                int o = m * 16 + quad * 4 + r;
                atomicAdd(&stats[o], s);
                atomicAdd(&stats[C_OUT + o], sq);
            }
        }
    }
}

// ---------------------------------------------------------------------------
// Kernel 4: finalize BN stats -> scale/shift
// ---------------------------------------------------------------------------
__global__ void k_finalize(const float* __restrict__ stats, float* __restrict__ ss,
                           const float* __restrict__ gamma,
                           const float* __restrict__ beta) {
    int o = threadIdx.x;
    if (o < C_OUT) {
        const float invN = 1.0f / (float)N_NODES;
        float mean = stats[o] * invN;
        float var = stats[C_OUT + o] * invN - mean * mean;
        float rstd = rsqrtf(var + 1e-3f);
        float sc = gamma[o] * rstd;
        ss[o] = sc;
        ss[C_OUT + o] = beta[o] - mean * sc;
    }
}

// ---------------------------------------------------------------------------
// Kernel 5: in-place BN + ReLU on y (= d_out), float4 vectorized
// ---------------------------------------------------------------------------
__global__ __launch_bounds__(256) void k_bn_relu(float* __restrict__ y,
                                                 const float* __restrict__ ss) {
    int o = blockIdx.y;
    int i = blockIdx.x * 256 + threadIdx.x;
    float sc = ss[o], sh = ss[C_OUT + o];
    if (i < N_NODES / 4) {
        float4* p = reinterpret_cast<float4*>(y + (size_t)o * N_NODES) + i;
        float4 v = *p;
        v.x = fmaxf(fmaf(v.x, sc, sh), 0.f);
        v.y = fmaxf(fmaf(v.y, sc, sh), 0.f);
        v.z = fmaxf(fmaf(v.z, sc, sh), 0.f);
        v.w = fmaxf(fmaf(v.w, sc, sh), 0.f);
        *p = v;
    }
}

extern "C" void kernel_launch(void* const* d_in, const int* in_sizes, int n_in,
                              void* d_out, int out_size, void* d_ws, size_t ws_size,
                              hipStream_t stream) {
    const float* data_in = (const float*)d_in[0];
    const int* neigh = (const int*)d_in[1];
    const float* W = (const float*)d_in[2];
    const float* gamma = (const float*)d_in[3];
    const float* beta = (const float*)d_in[4];
    float* out = (float*)d_out;

    char* ws = (char*)d_ws;
    ushort* xT = (ushort*)ws;                       // 150016*32*2   = 9,601,024 B
    ushort* A_re = (ushort*)(ws + 9601024);         // 64*864*2      =   110,592 B
    float* stats = (float*)(ws + 9711680);          // 256 floats (sum,sumsq,scale,shift)

    k_transpose<<<2344, 256, 0, stream>>>(data_in, xT);
    k_prep_w<<<(C_OUT * C_IN * K_TAPS + 255) / 256, 256, 0, stream>>>(W, A_re, stats);
    k_conv<<<(N_NODES + 255) / 256, 256, 0, stream>>>(xT, A_re, neigh, out, stats);
    k_finalize<<<1, 64, 0, stream>>>(stats, stats + 128, gamma, beta);
    k_bn_relu<<<dim3((N_NODES / 4 + 255) / 256, C_OUT), 256, 0, stream>>>(out,
                                                                          stats + 128);
}

// Round 2
// 184.913 us; speedup vs baseline: 2.0859x; 2.0859x over previous
//
#include <hip/hip_runtime.h>
#include <hip/hip_bf16.h>
#include <stdint.h>

#define N_NODES 150000
#define C_IN 32
#define C_OUT 64
#define K_TAPS 27
#define PF 3
#define NSLOTS 32

typedef __attribute__((ext_vector_type(8))) __bf16 bf16x8;
typedef __attribute__((ext_vector_type(4))) float f32x4;

__device__ __forceinline__ ushort f2bf(float f) {
    union { float f; uint32_t u; } v; v.f = f;
    uint32_t u = v.u;
    return (ushort)((u + 0x7FFFu + ((u >> 16) & 1u)) >> 16);
}

// ---------------------------------------------------------------------------
// Kernel 1: transpose x (32 x 150000 fp32) -> xT (150001 x 32 bf16), zero pad row
// ---------------------------------------------------------------------------
__global__ __launch_bounds__(256) void k_transpose(const float* __restrict__ x,
                                                   ushort* __restrict__ xT) {
    __shared__ float tile[32][65];
    int t = threadIdx.x;
    int nb = blockIdx.x * 64;
    int nl = t & 63, i4 = t >> 6;
#pragma unroll
    for (int rep = 0; rep < 8; ++rep) {
        int i = rep * 4 + i4;
        int n = nb + nl;
        tile[i][nl] = (n < N_NODES) ? x[(size_t)i * N_NODES + n] : 0.0f;
    }
    __syncthreads();
    int nr = t >> 2, c0 = (t & 3) * 8;
    int n = nb + nr;
    if (n <= N_NODES) {  // row N_NODES is the zero-pad row
        uint32_t w[4];
#pragma unroll
        for (int j = 0; j < 4; ++j) {
            ushort lo = f2bf(tile[c0 + 2 * j][nr]);
            ushort hi = f2bf(tile[c0 + 2 * j + 1][nr]);
            w[j] = (uint32_t)lo | ((uint32_t)hi << 16);
        }
        *reinterpret_cast<uint4*>(xT + (size_t)n * 32 + c0) =
            make_uint4(w[0], w[1], w[2], w[3]);
    }
}

// ---------------------------------------------------------------------------
// Kernel 2: repack W (64,32,27) fp32 -> A_frag, coalesced per (k,m):
//   A_frag[(k*4+m)*512 + lane*8 + j] = W[o = m*16+(lane&15)][i = (lane>>4)*8+j][k]
// Also zero the striped stats buffers.
// ---------------------------------------------------------------------------
__global__ __launch_bounds__(256) void k_prep_w(const float* __restrict__ W,
                                                ushort* __restrict__ A_frag,
                                                float* __restrict__ stats) {
    int tid = blockIdx.x * 256 + threadIdx.x;
    if (tid < NSLOTS * 128 + 128) stats[tid] = 0.0f;
    if (tid < C_OUT * C_IN * K_TAPS) {
        int j = tid & 7;
        int ln = (tid >> 3) & 63;
        int km = tid >> 9;
        int m = km & 3;
        int k = km >> 2;
        int o = m * 16 + (ln & 15);
        int i = (ln >> 4) * 8 + j;
        A_frag[tid] = f2bf(W[o * (C_IN * K_TAPS) + i * K_TAPS + k]);
    }
}

// ---------------------------------------------------------------------------
// Kernel 3: gather-GEMM. 1 wave / block, 32 nodes / wave, full C_OUT=64.
// Depth-3 register pipeline on both A (coalesced) and B (gather) fragments.
// ---------------------------------------------------------------------------
__global__ __launch_bounds__(64, 4) void k_conv(const ushort* __restrict__ xT,
                                                const ushort* __restrict__ A_frag,
                                                const int* __restrict__ neigh,
                                                float* __restrict__ y,
                                                float* __restrict__ stats) {
    __shared__ int soff[32 * K_TAPS];  // pre-scaled byte offsets into xT
    int t = threadIdx.x;
    int nb = blockIdx.x * 32;
    for (int j = t; j < 32 * K_TAPS; j += 64) {
        int ng = nb + j / K_TAPS;
        int idx = (ng < N_NODES) ? neigh[(size_t)nb * K_TAPS + j] : N_NODES;
        soff[j] = idx << 6;  // 64 B per xT row
    }
    __syncthreads();

    int l15 = t & 15, quad = t >> 4;
    int qoff = quad << 4;  // byte offset within a node row

    const char* xTb = (const char*)xT;
    const char* aB = (const char*)A_frag + (size_t)t * 16;

    f32x4 acc[4][2];
#pragma unroll
    for (int m = 0; m < 4; ++m)
#pragma unroll
        for (int g = 0; g < 2; ++g) acc[m][g] = (f32x4){0.f, 0.f, 0.f, 0.f};

    bf16x8 bb[PF][2], aa[PF][4];

#pragma unroll
    for (int s = 0; s < PF; ++s) {
#pragma unroll
        for (int g = 0; g < 2; ++g)
            bb[s][g] = *reinterpret_cast<const bf16x8*>(
                xTb + (uint32_t)soff[(g * 16 + l15) * K_TAPS + s] + qoff);
#pragma unroll
        for (int m = 0; m < 4; ++m)
            aa[s][m] = *reinterpret_cast<const bf16x8*>(aB + ((size_t)(s * 4 + m) << 10));
    }

#pragma unroll 3
    for (int k = 0; k < K_TAPS; ++k) {
        int cur = k % PF;
#pragma unroll
        for (int m = 0; m < 4; ++m)
#pragma unroll
            for (int g = 0; g < 2; ++g)
                acc[m][g] = __builtin_amdgcn_mfma_f32_16x16x32_bf16(
                    aa[cur][m], bb[cur][g], acc[m][g], 0, 0, 0);
        if (k < K_TAPS - PF) {
            int kn = k + PF;
#pragma unroll
            for (int g = 0; g < 2; ++g)
                bb[cur][g] = *reinterpret_cast<const bf16x8*>(
                    xTb + (uint32_t)soff[(g * 16 + l15) * K_TAPS + kn] + qoff);
#pragma unroll
            for (int m = 0; m < 4; ++m)
                aa[cur][m] = *reinterpret_cast<const bf16x8*>(
                    aB + ((size_t)(kn * 4 + m) << 10));
        }
    }

    // store y tile (C/D: col=l15 -> node, row=quad*4+r -> channel)
#pragma unroll
    for (int m = 0; m < 4; ++m) {
        int obase = m * 16 + quad * 4;
#pragma unroll
        for (int g = 0; g < 2; ++g) {
            int n = nb + g * 16 + l15;
            if (n < N_NODES) {
#pragma unroll
                for (int r = 0; r < 4; ++r)
                    y[(size_t)(obase + r) * N_NODES + n] = acc[m][g][r];
            }
        }
    }

    // per-channel partial sums, striped over NSLOTS buffers
    int slot = blockIdx.x & (NSLOTS - 1);
#pragma unroll
    for (int m = 0; m < 4; ++m) {
#pragma unroll
        for (int r = 0; r < 4; ++r) {
            float s = 0.f, sq = 0.f;
#pragma unroll
            for (int g = 0; g < 2; ++g) {
                float v = acc[m][g][r];
                s += v;
                sq += v * v;
            }
#pragma unroll
            for (int d = 1; d < 16; d <<= 1) {
                s += __shfl_xor(s, d);
                sq += __shfl_xor(sq, d);
            }
            if (l15 == 0) {
                int o = m * 16 + quad * 4 + r;
                atomicAdd(&stats[slot * 128 + o], s);
                atomicAdd(&stats[slot * 128 + 64 + o], sq);
            }
        }
    }
}

// ---------------------------------------------------------------------------
// Kernel 4: finalize BN stats -> scale/shift
// ---------------------------------------------------------------------------
__global__ void k_finalize(const float* __restrict__ stats, float* __restrict__ ss,
                           const float* __restrict__ gamma,
                           const float* __restrict__ beta) {
    int o = threadIdx.x;
    if (o < C_OUT) {
        float s = 0.f, sq = 0.f;
        for (int c = 0; c < NSLOTS; ++c) {
            s += stats[c * 128 + o];
            sq += stats[c * 128 + 64 + o];
        }
        const float invN = 1.0f / (float)N_NODES;
        float mean = s * invN;
        float var = sq * invN - mean * mean;
        float rstd = rsqrtf(var + 1e-3f);
        float sc = gamma[o] * rstd;
        ss[o] = sc;
        ss[C_OUT + o] = beta[o] - mean * sc;
    }
}

// ---------------------------------------------------------------------------
// Kernel 5: in-place BN + ReLU on y (= d_out), float4 vectorized
// ---------------------------------------------------------------------------
__global__ __launch_bounds__(256) void k_bn_relu(float* __restrict__ y,
                                                 const float* __restrict__ ss) {
    int o = blockIdx.y;
    int i = blockIdx.x * 256 + threadIdx.x;
    float sc = ss[o], sh = ss[C_OUT + o];
    if (i < N_NODES / 4) {
        float4* p = reinterpret_cast<float4*>(y + (size_t)o * N_NODES) + i;
        float4 v = *p;
        v.x = fmaxf(fmaf(v.x, sc, sh), 0.f);
        v.y = fmaxf(fmaf(v.y, sc, sh), 0.f);
        v.z = fmaxf(fmaf(v.z, sc, sh), 0.f);
        v.w = fmaxf(fmaf(v.w, sc, sh), 0.f);
        *p = v;
    }
}

extern "C" void kernel_launch(void* const* d_in, const int* in_sizes, int n_in,
                              void* d_out, int out_size, void* d_ws, size_t ws_size,
                              hipStream_t stream) {
    const float* data_in = (const float*)d_in[0];
    const int* neigh = (const int*)d_in[1];
    const float* W = (const float*)d_in[2];
    const float* gamma = (const float*)d_in[3];
    const float* beta = (const float*)d_in[4];
    float* out = (float*)d_out;

    char* ws = (char*)d_ws;
    ushort* xT = (ushort*)ws;                     // 150016*32*2 = 9,601,024 B
    ushort* A_frag = (ushort*)(ws + 9601024);     // 64*864*2    =   110,592 B
    float* stats = (float*)(ws + 9711616);        // 32*128 partials + 128 ss
    float* ss = stats + NSLOTS * 128;

    k_transpose<<<2344, 256, 0, stream>>>(data_in, xT);
    k_prep_w<<<(C_OUT * C_IN * K_TAPS + 255) / 256, 256, 0, stream>>>(W, A_frag, stats);
    k_conv<<<(N_NODES + 31) / 32, 64, 0, stream>>>(xT, A_frag, neigh, out, stats);
    k_finalize<<<1, 64, 0, stream>>>(stats, ss, gamma, beta);
    k_bn_relu<<<dim3((N_NODES / 4 + 255) / 256, C_OUT), 256, 0, stream>>>(out, ss);
}